// Round 2
// baseline (2820.922 us; speedup 1.0000x reference)
//
#include <hip/hip_runtime.h>

#define NEG_SLOPE 0.2f

// ---------- float-ordered key for atomic max on unsigned ----------
__device__ __forceinline__ unsigned fkey(float f) {
  unsigned u = __float_as_uint(f);
  return (u & 0x80000000u) ? ~u : (u | 0x80000000u);
}
__device__ __forceinline__ float fdecode(unsigned k) {
  unsigned u = (k & 0x80000000u) ? (k ^ 0x80000000u) : ~k;
  return __uint_as_float(u);
}

// ---------- Y[n,H] = X[n,K] @ W[K,H] ----------
template<int K, int H>
__global__ void linear_kernel(const float* __restrict__ X, const float* __restrict__ W,
                              float* __restrict__ Y, int n) {
  __shared__ float Ws[K * H];
  for (int i = threadIdx.x; i < K * H; i += blockDim.x) Ws[i] = W[i];
  __syncthreads();
  int idx = blockIdx.x * blockDim.x + threadIdx.x;
  int total = n * H;
  if (idx >= total) return;
  int nrow = idx / H;
  int h = idx - nrow * H;
  const float* xr = X + (size_t)nrow * K;
  float acc = 0.f;
#pragma unroll 8
  for (int k = 0; k < K; ++k) acc = fmaf(xr[k], Ws[k * H + h], acc);
  Y[idx] = acc;
}

// ---------- per-edge logits e = att . leakyrelu(xl[src] + xr[dst]); atomic max per dst ----------
template<int H>
__global__ void edge_logits_kernel(const float* __restrict__ XL, const float* __restrict__ XR,
                                   const int* __restrict__ ei, const float* __restrict__ att,
                                   float* __restrict__ e, unsigned* __restrict__ mkey,
                                   int nE, int nN) {
  __shared__ float atts[H];
  for (int i = threadIdx.x; i < H; i += blockDim.x) atts[i] = att[i];
  __syncthreads();
  int t = blockIdx.x * blockDim.x + threadIdx.x;
  int total = nE + nN;
  if (t >= total) return;
  int s, d;
  if (t < nE) { s = ei[t]; d = ei[nE + t]; } else { s = t - nE; d = s; }
  const float4* a = (const float4*)(XL + (size_t)s * H);
  const float4* b = (const float4*)(XR + (size_t)d * H);
  const float4* w4 = (const float4*)atts;
  float acc = 0.f;
#pragma unroll
  for (int i = 0; i < H / 4; ++i) {
    float4 u = a[i], v = b[i], w = w4[i];
    float f;
    f = u.x + v.x; f = f > 0.f ? f : NEG_SLOPE * f; acc = fmaf(f, w.x, acc);
    f = u.y + v.y; f = f > 0.f ? f : NEG_SLOPE * f; acc = fmaf(f, w.y, acc);
    f = u.z + v.z; f = f > 0.f ? f : NEG_SLOPE * f; acc = fmaf(f, w.z, acc);
    f = u.w + v.w; f = f > 0.f ? f : NEG_SLOPE * f; acc = fmaf(f, w.w, acc);
  }
  e[t] = acc;
  atomicMax(&mkey[d], fkey(acc));
}

// ---------- ex = exp(e - m[dst]); denom[dst] += ex  (in-place on e) ----------
__global__ void edge_exp_kernel(float* __restrict__ e, const int* __restrict__ ei,
                                const unsigned* __restrict__ mkey, float* __restrict__ denom,
                                int nE, int nN) {
  int t = blockIdx.x * blockDim.x + threadIdx.x;
  int total = nE + nN;
  if (t >= total) return;
  int d = (t < nE) ? ei[nE + t] : (t - nE);
  float m = fdecode(mkey[d]);
  float v = expf(e[t] - m);
  e[t] = v;
  atomicAdd(&denom[d], v);
}

// ---------- out[dst] += (ex/denom[dst]) * xl[src], float4 chunks ----------
template<int H>
__global__ void edge_aggregate_kernel(const float* __restrict__ XL, const int* __restrict__ ei,
                                      const float* __restrict__ ex, const float* __restrict__ denom,
                                      float* __restrict__ out, int nE, int nN) {
  const int C4 = H / 4;
  long long idx = (long long)blockIdx.x * blockDim.x + threadIdx.x;
  long long total = (long long)(nE + nN) * C4;
  if (idx >= total) return;
  int t = (int)(idx / C4);
  int c = (int)(idx - (long long)t * C4);
  int s, d;
  if (t < nE) { s = ei[t]; d = ei[nE + t]; } else { s = t - nE; d = s; }
  float alpha = ex[t] / (denom[d] + 1e-16f);
  float4 u = ((const float4*)(XL + (size_t)s * H))[c];
  float* o = out + (size_t)d * H + c * 4;
  atomicAdd(o + 0, alpha * u.x);
  atomicAdd(o + 1, alpha * u.y);
  atomicAdd(o + 2, alpha * u.z);
  atomicAdd(o + 3, alpha * u.w);
}

// ---------- y = relu(y + b[h]) in place ----------
__global__ void bias_relu_kernel(float* __restrict__ y, const float* __restrict__ b,
                                 int total, int H) {
  int i = blockIdx.x * blockDim.x + threadIdx.x;
  if (i >= total) return;
  float v = y[i] + b[i % H];
  y[i] = v > 0.f ? v : 0.f;
}

// ---------- out[l] = sum_k hs[k]*hd[k]*(Wp[k,0]+Wp[k,1]) + bp0+bp1 ----------
__global__ void predict_kernel(const float* __restrict__ h, const int* __restrict__ eli,
                               const float* __restrict__ Wp, const float* __restrict__ bp,
                               float* __restrict__ out, int L) {
  int l = blockIdx.x * blockDim.x + threadIdx.x;
  if (l >= L) return;
  int s = eli[l], d = eli[L + l];
  const float4* a = (const float4*)(h + (size_t)s * 64);
  const float4* b = (const float4*)(h + (size_t)d * 64);
  const float4* wp = (const float4*)Wp;  // pairs: (w[k,0], w[k,1], w[k+1,0], w[k+1,1])
  float acc = bp[0] + bp[1];
#pragma unroll
  for (int i = 0; i < 16; ++i) {
    float4 u = a[i], v = b[i];
    float4 w0 = wp[2 * i];      // k=4i, 4i+1
    float4 w1 = wp[2 * i + 1];  // k=4i+2, 4i+3
    acc = fmaf(u.x * v.x, w0.x + w0.y, acc);
    acc = fmaf(u.y * v.y, w0.z + w0.w, acc);
    acc = fmaf(u.z * v.z, w1.x + w1.y, acc);
    acc = fmaf(u.w * v.w, w1.z + w1.w, acc);
  }
  out[l] = acc;
}

static inline int cdiv(long long a, int b) { return (int)((a + b - 1) / b); }

extern "C" void kernel_launch(void* const* d_in, const int* in_sizes, int n_in,
                              void* d_out, int out_size, void* d_ws, size_t ws_size,
                              hipStream_t stream) {
  const float* x    = (const float*)d_in[0];
  const int*   ei   = (const int*)d_in[1];
  const int*   eli  = (const int*)d_in[2];
  const float* Wl1  = (const float*)d_in[3];
  const float* Wr1  = (const float*)d_in[4];
  const float* att1 = (const float*)d_in[5];
  const float* b1   = (const float*)d_in[6];
  const float* Wl2  = (const float*)d_in[7];
  const float* Wr2  = (const float*)d_in[8];
  const float* att2 = (const float*)d_in[9];
  const float* b2   = (const float*)d_in[10];
  const float* Wp   = (const float*)d_in[11];
  const float* bp   = (const float*)d_in[12];
  float* out = (float*)d_out;

  const int N = in_sizes[0] / 128;
  const int E = in_sizes[1] / 2;
  const int L = in_sizes[2] / 2;
  const int T = E + N;  // edges incl. self-loops

  // workspace layout (floats)
  float* A = (float*)d_ws;            // [N*96] xl1, later xr2
  float* B = A + (size_t)N * 96;      // [N*96] xr1, later xl2
  float* C = B + (size_t)N * 96;      // [N*96] agg1/h1, later agg2/h2
  float* D = C + (size_t)N * 96;      // [E+N]  e / ex
  unsigned* M = (unsigned*)(D + T);   // [N] max keys
  float* S = (float*)(M + N);         // [N] denom

  const int BS = 256;

  // ---------------- layer 1 (128 -> 96) ----------------
  linear_kernel<128, 96><<<cdiv((long long)N * 96, BS), BS, 0, stream>>>(x, Wl1, A, N);
  linear_kernel<128, 96><<<cdiv((long long)N * 96, BS), BS, 0, stream>>>(x, Wr1, B, N);

  hipMemsetAsync(M, 0, (size_t)N * 4, stream);
  hipMemsetAsync(S, 0, (size_t)N * 4, stream);
  hipMemsetAsync(C, 0, (size_t)N * 96 * 4, stream);

  edge_logits_kernel<96><<<cdiv(T, BS), BS, 0, stream>>>(A, B, ei, att1, D, M, E, N);
  edge_exp_kernel<<<cdiv(T, BS), BS, 0, stream>>>(D, ei, M, S, E, N);
  edge_aggregate_kernel<96><<<cdiv((long long)T * 24, BS), BS, 0, stream>>>(A, ei, D, S, C, E, N);
  bias_relu_kernel<<<cdiv((long long)N * 96, BS), BS, 0, stream>>>(C, b1, N * 96, 96);

  // ---------------- layer 2 (96 -> 64) ----------------
  linear_kernel<96, 64><<<cdiv((long long)N * 64, BS), BS, 0, stream>>>(C, Wl2, B, N);
  linear_kernel<96, 64><<<cdiv((long long)N * 64, BS), BS, 0, stream>>>(C, Wr2, A, N);

  hipMemsetAsync(M, 0, (size_t)N * 4, stream);
  hipMemsetAsync(S, 0, (size_t)N * 4, stream);
  hipMemsetAsync(C, 0, (size_t)N * 64 * 4, stream);

  edge_logits_kernel<64><<<cdiv(T, BS), BS, 0, stream>>>(B, A, ei, att2, D, M, E, N);
  edge_exp_kernel<<<cdiv(T, BS), BS, 0, stream>>>(D, ei, M, S, E, N);
  edge_aggregate_kernel<64><<<cdiv((long long)T * 16, BS), BS, 0, stream>>>(B, ei, D, S, C, E, N);
  bias_relu_kernel<<<cdiv((long long)N * 64, BS), BS, 0, stream>>>(C, b2, N * 64, 64);

  // ---------------- link predictor ----------------
  predict_kernel<<<cdiv(L, BS), BS, 0, stream>>>(C, eli, Wp, bp, out, L);
}

// Round 3
// 961.547 us; speedup vs baseline: 2.9337x; 2.9337x over previous
//
#include <hip/hip_runtime.h>

#define NEG_SLOPE 0.2f

// ---------- Y[n,H] = X[n,K] @ W[K,H] ----------
template<int K, int H>
__global__ void linear_kernel(const float* __restrict__ X, const float* __restrict__ W,
                              float* __restrict__ Y, int n) {
  __shared__ float Ws[K * H];
  for (int i = threadIdx.x; i < K * H; i += blockDim.x) Ws[i] = W[i];
  __syncthreads();
  int idx = blockIdx.x * blockDim.x + threadIdx.x;
  int total = n * H;
  if (idx >= total) return;
  int nrow = idx / H;
  int h = idx - nrow * H;
  const float* xr = X + (size_t)nrow * K;
  float acc = 0.f;
#pragma unroll 8
  for (int k = 0; k < K; ++k) acc = fmaf(xr[k], Ws[k * H + h], acc);
  Y[idx] = acc;
}

// ---------- CSR build: histogram of dst ----------
__global__ void hist_kernel(const int* __restrict__ ei, int* __restrict__ deg, int nE, int nN) {
  int t = blockIdx.x * blockDim.x + threadIdx.x;
  if (t >= nE + nN) return;
  int d = (t < nE) ? ei[nE + t] : (t - nE);
  atomicAdd(&deg[d], 1);
}

// ---------- CSR build: single-block streaming exclusive scan ----------
__global__ void scan_kernel(const int* __restrict__ deg, int* __restrict__ rowptr, int n) {
  __shared__ int wsum[16];
  __shared__ int carry_s;
  int lane = threadIdx.x & 63;
  int wid = threadIdx.x >> 6;
  if (threadIdx.x == 0) carry_s = 0;
  __syncthreads();
  for (int base = 0; base < n; base += 1024) {
    int i = base + threadIdx.x;
    int v = (i < n) ? deg[i] : 0;
    int sc = v;
#pragma unroll
    for (int off = 1; off < 64; off <<= 1) {
      int t = __shfl_up(sc, off);
      if (lane >= off) sc += t;
    }
    if (lane == 63) wsum[wid] = sc;
    __syncthreads();
    if (wid == 0 && lane < 16) {
      int w = wsum[lane];
#pragma unroll
      for (int off = 1; off < 16; off <<= 1) {
        int t = __shfl_up(w, off, 16);
        if (lane >= off) w += t;
      }
      wsum[lane] = w;
    }
    __syncthreads();
    int waveoff = (wid == 0) ? 0 : wsum[wid - 1];
    int total = wsum[15];
    int inc = carry_s + waveoff + sc;
    if (i < n) rowptr[i + 1] = inc;
    __syncthreads();
    if (threadIdx.x == 0) carry_s += total;
    __syncthreads();
  }
  if (threadIdx.x == 0) rowptr[0] = 0;
}

// ---------- CSR build: fill src ids into dst buckets ----------
__global__ void fill_kernel(const int* __restrict__ ei, int* __restrict__ cnt,
                            const int* __restrict__ rowptr, int* __restrict__ ebuf,
                            int nE, int nN) {
  int t = blockIdx.x * blockDim.x + threadIdx.x;
  if (t >= nE + nN) return;
  int s, d;
  if (t < nE) { s = ei[t]; d = ei[nE + t]; } else { s = t - nE; d = s; }
  int pos = rowptr[d] + atomicAdd(&cnt[d], 1);
  ebuf[pos] = s;
}

// ---------- fused GATv2 layer: one wave per dst node, online softmax, no atomics ----------
// out[d,:] = relu( (sum_e exp(e_e - m) * xl[src_e,:]) / (sum_e exp(e_e - m) + 1e-16) + bias )
template<int H>
__global__ void gat_fused_kernel(const float* __restrict__ XL, const float* __restrict__ XR,
                                 const int* __restrict__ rowptr, const int* __restrict__ ebuf,
                                 const float* __restrict__ att, const float* __restrict__ bias,
                                 float* __restrict__ out, int nN) {
  int lane = threadIdx.x & 63;
  int wid = threadIdx.x >> 6;
  int d = blockIdx.x * (blockDim.x >> 6) + wid;
  if (d >= nN) return;
  constexpr bool TWO = (H > 64);
  const int c0 = lane;
  const int c1 = 64 + lane;
  const bool has1 = TWO && (lane < H - 64);
  float xr0 = XR[(size_t)d * H + c0];
  float xr1 = has1 ? XR[(size_t)d * H + c1] : 0.f;
  float a0 = att[c0];
  float a1 = has1 ? att[c1] : 0.f;
  float m = -1e30f, den = 0.f, o0 = 0.f, o1 = 0.f;
  int beg = rowptr[d], end = rowptr[d + 1];
  for (int i = beg; i < end; ++i) {
    int s = ebuf[i];
    const float* xlr = XL + (size_t)s * H;
    float x0 = xlr[c0];
    float x1 = has1 ? xlr[c1] : 0.f;
    float f0 = x0 + xr0; f0 = f0 > 0.f ? f0 : NEG_SLOPE * f0;
    float part = f0 * a0;
    if (has1) { float f1 = x1 + xr1; f1 = f1 > 0.f ? f1 : NEG_SLOPE * f1; part = fmaf(f1, a1, part); }
#pragma unroll
    for (int off = 32; off; off >>= 1) part += __shfl_xor(part, off);
    float e = part;
    if (e > m) {
      float scl = __expf(m - e);
      den *= scl; o0 *= scl; o1 *= scl; m = e;
    }
    float p = __expf(e - m);
    den += p;
    o0 = fmaf(p, x0, o0);
    if (has1) o1 = fmaf(p, x1, o1);
  }
  float inv = 1.f / (den + 1e-16f);
  float y0 = fmaf(o0, inv, bias[c0]); y0 = y0 > 0.f ? y0 : 0.f;
  out[(size_t)d * H + c0] = y0;
  if (has1) {
    float y1 = fmaf(o1, inv, bias[c1]); y1 = y1 > 0.f ? y1 : 0.f;
    out[(size_t)d * H + c1] = y1;
  }
}

// ---------- out[l] = sum_k hs[k]*hd[k]*(Wp[k,0]+Wp[k,1]) + bp0+bp1 ----------
__global__ void predict_kernel(const float* __restrict__ h, const int* __restrict__ eli,
                               const float* __restrict__ Wp, const float* __restrict__ bp,
                               float* __restrict__ out, int L) {
  int l = blockIdx.x * blockDim.x + threadIdx.x;
  if (l >= L) return;
  int s = eli[l], d = eli[L + l];
  const float4* a = (const float4*)(h + (size_t)s * 64);
  const float4* b = (const float4*)(h + (size_t)d * 64);
  const float4* wp = (const float4*)Wp;
  float acc = bp[0] + bp[1];
#pragma unroll
  for (int i = 0; i < 16; ++i) {
    float4 u = a[i], v = b[i];
    float4 w0 = wp[2 * i];
    float4 w1 = wp[2 * i + 1];
    acc = fmaf(u.x * v.x, w0.x + w0.y, acc);
    acc = fmaf(u.y * v.y, w0.z + w0.w, acc);
    acc = fmaf(u.z * v.z, w1.x + w1.y, acc);
    acc = fmaf(u.w * v.w, w1.z + w1.w, acc);
  }
  out[l] = acc;
}

static inline int cdiv(long long a, int b) { return (int)((a + b - 1) / b); }

extern "C" void kernel_launch(void* const* d_in, const int* in_sizes, int n_in,
                              void* d_out, int out_size, void* d_ws, size_t ws_size,
                              hipStream_t stream) {
  const float* x    = (const float*)d_in[0];
  const int*   ei   = (const int*)d_in[1];
  const int*   eli  = (const int*)d_in[2];
  const float* Wl1  = (const float*)d_in[3];
  const float* Wr1  = (const float*)d_in[4];
  const float* att1 = (const float*)d_in[5];
  const float* b1   = (const float*)d_in[6];
  const float* Wl2  = (const float*)d_in[7];
  const float* Wr2  = (const float*)d_in[8];
  const float* att2 = (const float*)d_in[9];
  const float* b2   = (const float*)d_in[10];
  const float* Wp   = (const float*)d_in[11];
  const float* bp   = (const float*)d_in[12];
  float* out = (float*)d_out;

  const int N = in_sizes[0] / 128;
  const int E = in_sizes[1] / 2;
  const int L = in_sizes[2] / 2;
  const int T = E + N;

  // workspace layout
  float* A = (float*)d_ws;            // [N*96] xl1, later xr2
  float* B = A + (size_t)N * 96;      // [N*96] xr1, later xl2
  float* C = B + (size_t)N * 96;      // [N*96] h1, later h2
  int* deg    = (int*)(C + (size_t)N * 96);  // [N]
  int* cnt    = deg + N;                     // [N]
  int* rowptr = cnt + N;                     // [N+1]
  int* ebuf   = rowptr + N + 1;              // [T] src per CSR slot

  const int BS = 256;

  // ---------------- CSR build (once, shared by both layers) ----------------
  hipMemsetAsync(deg, 0, (size_t)N * 4, stream);
  hipMemsetAsync(cnt, 0, (size_t)N * 4, stream);
  hist_kernel<<<cdiv(T, BS), BS, 0, stream>>>(ei, deg, E, N);
  scan_kernel<<<1, 1024, 0, stream>>>(deg, rowptr, N);
  fill_kernel<<<cdiv(T, BS), BS, 0, stream>>>(ei, cnt, rowptr, ebuf, E, N);

  // ---------------- layer 1 (128 -> 96) ----------------
  linear_kernel<128, 96><<<cdiv((long long)N * 96, BS), BS, 0, stream>>>(x, Wl1, A, N);
  linear_kernel<128, 96><<<cdiv((long long)N * 96, BS), BS, 0, stream>>>(x, Wr1, B, N);
  gat_fused_kernel<96><<<cdiv(N, BS / 64), BS, 0, stream>>>(A, B, rowptr, ebuf, att1, b1, C, N);

  // ---------------- layer 2 (96 -> 64) ----------------
  linear_kernel<96, 64><<<cdiv((long long)N * 64, BS), BS, 0, stream>>>(C, Wl2, B, N);
  linear_kernel<96, 64><<<cdiv((long long)N * 64, BS), BS, 0, stream>>>(C, Wr2, A, N);
  gat_fused_kernel<64><<<cdiv(N, BS / 64), BS, 0, stream>>>(B, A, rowptr, ebuf, att2, b2, C, N);

  // ---------------- link predictor ----------------
  predict_kernel<<<cdiv(L, BS), BS, 0, stream>>>(C, eli, Wp, bp, out, L);
}

// Round 5
// 478.077 us; speedup vs baseline: 5.9006x; 2.0113x over previous
//
#include <hip/hip_runtime.h>

#define NEG_SLOPE 0.2f

// ---------- register-tiled fp32 GEMM: Y[n,H] = X[n,K] @ W[K,H] ----------
// BM rows x H cols per block; K processed in BK chunks. X chunk staged
// transposed in LDS (padded stride), W chunk row-major. 4x4 micro-tile/thread.
template<int K, int H, int BK, int BM, int NT>
__global__ __launch_bounds__(NT) void gemm_kernel(const float* __restrict__ X,
                                                  const float* __restrict__ W,
                                                  float* __restrict__ Y, int n) {
  constexpr int TM = 4, TN = 4;
  constexpr int CG = H / TN;   // col groups
  constexpr int RG = BM / TM;  // row groups
  static_assert(CG * RG == NT, "thread grid mismatch");
  constexpr int XS = BM + 4;   // padded LDS stride (16B-aligned, bank-spread)
  __shared__ float Xs[BK][XS];
  __shared__ float Ws[BK][H];
  const int tid = threadIdx.x;
  const int row0 = blockIdx.x * BM;
  const int cg = tid % CG, rg = tid / CG;
  float acc[TM][TN] = {};

  for (int kc = 0; kc < K; kc += BK) {
    // stage W chunk (contiguous float4 copy)
    for (int i = tid; i < BK * H / 4; i += NT)
      ((float4*)&Ws[0][0])[i] = ((const float4*)(W + (size_t)kc * H))[i];
    // stage X chunk transposed
    for (int i = tid; i < BM * (BK / 4); i += NT) {
      int r = i / (BK / 4), kq = i % (BK / 4);
      int gr = row0 + r; if (gr >= n) gr = n - 1;
      float4 v = ((const float4*)(X + (size_t)gr * K + kc))[kq];
      Xs[kq * 4 + 0][r] = v.x;
      Xs[kq * 4 + 1][r] = v.y;
      Xs[kq * 4 + 2][r] = v.z;
      Xs[kq * 4 + 3][r] = v.w;
    }
    __syncthreads();
#pragma unroll 8
    for (int k = 0; k < BK; ++k) {
      float4 xv = *(const float4*)&Xs[k][rg * TM];
      float4 wv = *(const float4*)&Ws[k][cg * TN];
      acc[0][0] = fmaf(xv.x, wv.x, acc[0][0]);
      acc[0][1] = fmaf(xv.x, wv.y, acc[0][1]);
      acc[0][2] = fmaf(xv.x, wv.z, acc[0][2]);
      acc[0][3] = fmaf(xv.x, wv.w, acc[0][3]);
      acc[1][0] = fmaf(xv.y, wv.x, acc[1][0]);
      acc[1][1] = fmaf(xv.y, wv.y, acc[1][1]);
      acc[1][2] = fmaf(xv.y, wv.z, acc[1][2]);
      acc[1][3] = fmaf(xv.y, wv.w, acc[1][3]);
      acc[2][0] = fmaf(xv.z, wv.x, acc[2][0]);
      acc[2][1] = fmaf(xv.z, wv.y, acc[2][1]);
      acc[2][2] = fmaf(xv.z, wv.z, acc[2][2]);
      acc[2][3] = fmaf(xv.z, wv.w, acc[2][3]);
      acc[3][0] = fmaf(xv.w, wv.x, acc[3][0]);
      acc[3][1] = fmaf(xv.w, wv.y, acc[3][1]);
      acc[3][2] = fmaf(xv.w, wv.z, acc[3][2]);
      acc[3][3] = fmaf(xv.w, wv.w, acc[3][3]);
    }
    __syncthreads();
  }
  const int c0 = cg * TN;
#pragma unroll
  for (int i = 0; i < TM; ++i) {
    int gr = row0 + rg * TM + i;
    if (gr < n) {
      float4 o = make_float4(acc[i][0], acc[i][1], acc[i][2], acc[i][3]);
      *(float4*)(Y + (size_t)gr * H + c0) = o;
    }
  }
}

// ---------- CSR build: histogram of dst ----------
__global__ void hist_kernel(const int* __restrict__ ei, int* __restrict__ deg, int nE, int nN) {
  int t = blockIdx.x * blockDim.x + threadIdx.x;
  if (t >= nE + nN) return;
  int d = (t < nE) ? ei[nE + t] : (t - nE);
  atomicAdd(&deg[d], 1);
}

// ---------- CSR build: single-block streaming exclusive scan ----------
__global__ void scan_kernel(const int* __restrict__ deg, int* __restrict__ rowptr, int n) {
  __shared__ int wsum[16];
  __shared__ int carry_s;
  int lane = threadIdx.x & 63;
  int wid = threadIdx.x >> 6;
  if (threadIdx.x == 0) carry_s = 0;
  __syncthreads();
  for (int base = 0; base < n; base += 1024) {
    int i = base + threadIdx.x;
    int v = (i < n) ? deg[i] : 0;
    int sc = v;
#pragma unroll
    for (int off = 1; off < 64; off <<= 1) {
      int t = __shfl_up(sc, off);
      if (lane >= off) sc += t;
    }
    if (lane == 63) wsum[wid] = sc;
    __syncthreads();
    if (wid == 0 && lane < 16) {
      int w = wsum[lane];
#pragma unroll
      for (int off = 1; off < 16; off <<= 1) {
        int t = __shfl_up(w, off, 16);
        if (lane >= off) w += t;
      }
      wsum[lane] = w;
    }
    __syncthreads();
    int waveoff = (wid == 0) ? 0 : wsum[wid - 1];
    int total = wsum[15];
    int inc = carry_s + waveoff + sc;
    if (i < n) rowptr[i + 1] = inc;
    __syncthreads();
    if (threadIdx.x == 0) carry_s += total;
    __syncthreads();
  }
  if (threadIdx.x == 0) rowptr[0] = 0;
}

// ---------- CSR build: fill src ids into dst buckets ----------
__global__ void fill_kernel(const int* __restrict__ ei, int* __restrict__ cnt,
                            const int* __restrict__ rowptr, int* __restrict__ ebuf,
                            int nE, int nN) {
  int t = blockIdx.x * blockDim.x + threadIdx.x;
  if (t >= nE + nN) return;
  int s, d;
  if (t < nE) { s = ei[t]; d = ei[nE + t]; } else { s = t - nE; d = s; }
  int pos = rowptr[d] + atomicAdd(&cnt[d], 1);
  ebuf[pos] = s;
}

// ---------- fused GATv2 layer: one wave per dst node, online softmax, no atomics ----------
template<int H>
__global__ void gat_fused_kernel(const float* __restrict__ XL, const float* __restrict__ XR,
                                 const int* __restrict__ rowptr, const int* __restrict__ ebuf,
                                 const float* __restrict__ att, const float* __restrict__ bias,
                                 float* __restrict__ out, int nN) {
  int lane = threadIdx.x & 63;
  int wid = threadIdx.x >> 6;
  int d = blockIdx.x * (blockDim.x >> 6) + wid;
  if (d >= nN) return;
  constexpr bool TWO = (H > 64);
  const int c0 = lane;
  const int c1 = 64 + lane;
  const bool has1 = TWO && (lane < H - 64);
  float xr0 = XR[(size_t)d * H + c0];
  float xr1 = has1 ? XR[(size_t)d * H + c1] : 0.f;
  float a0 = att[c0];
  float a1 = has1 ? att[c1] : 0.f;
  float m = -1e30f, den = 0.f, o0 = 0.f, o1 = 0.f;
  int beg = rowptr[d], end = rowptr[d + 1];
  for (int i = beg; i < end; ++i) {
    int s = ebuf[i];
    const float* xlr = XL + (size_t)s * H;
    float x0 = xlr[c0];
    float x1 = has1 ? xlr[c1] : 0.f;
    float f0 = x0 + xr0; f0 = f0 > 0.f ? f0 : NEG_SLOPE * f0;
    float part = f0 * a0;
    if (has1) { float f1 = x1 + xr1; f1 = f1 > 0.f ? f1 : NEG_SLOPE * f1; part = fmaf(f1, a1, part); }
#pragma unroll
    for (int off = 32; off; off >>= 1) part += __shfl_xor(part, off);
    float e = part;
    if (e > m) {
      float scl = __expf(m - e);
      den *= scl; o0 *= scl; o1 *= scl; m = e;
    }
    float p = __expf(e - m);
    den += p;
    o0 = fmaf(p, x0, o0);
    if (has1) o1 = fmaf(p, x1, o1);
  }
  float inv = 1.f / (den + 1e-16f);
  float y0 = fmaf(o0, inv, bias[c0]); y0 = y0 > 0.f ? y0 : 0.f;
  out[(size_t)d * H + c0] = y0;
  if (has1) {
    float y1 = fmaf(o1, inv, bias[c1]); y1 = y1 > 0.f ? y1 : 0.f;
    out[(size_t)d * H + c1] = y1;
  }
}

// ---------- out[l] = sum_k hs[k]*hd[k]*(Wp[k,0]+Wp[k,1]) + bp0+bp1 ----------
__global__ void predict_kernel(const float* __restrict__ h, const int* __restrict__ eli,
                               const float* __restrict__ Wp, const float* __restrict__ bp,
                               float* __restrict__ out, int L) {
  int l = blockIdx.x * blockDim.x + threadIdx.x;
  if (l >= L) return;
  int s = eli[l], d = eli[L + l];
  const float4* a = (const float4*)(h + (size_t)s * 64);
  const float4* b = (const float4*)(h + (size_t)d * 64);
  const float4* wp = (const float4*)Wp;
  float acc = bp[0] + bp[1];
#pragma unroll
  for (int i = 0; i < 16; ++i) {
    float4 u = a[i], v = b[i];
    float4 w0 = wp[2 * i];
    float4 w1 = wp[2 * i + 1];
    acc = fmaf(u.x * v.x, w0.x + w0.y, acc);
    acc = fmaf(u.y * v.y, w0.z + w0.w, acc);
    acc = fmaf(u.z * v.z, w1.x + w1.y, acc);
    acc = fmaf(u.w * v.w, w1.z + w1.w, acc);
  }
  out[l] = acc;
}

static inline int cdiv(long long a, int b) { return (int)((a + b - 1) / b); }

extern "C" void kernel_launch(void* const* d_in, const int* in_sizes, int n_in,
                              void* d_out, int out_size, void* d_ws, size_t ws_size,
                              hipStream_t stream) {
  const float* x    = (const float*)d_in[0];
  const int*   ei   = (const int*)d_in[1];
  const int*   eli  = (const int*)d_in[2];
  const float* Wl1  = (const float*)d_in[3];
  const float* Wr1  = (const float*)d_in[4];
  const float* att1 = (const float*)d_in[5];
  const float* b1   = (const float*)d_in[6];
  const float* Wl2  = (const float*)d_in[7];
  const float* Wr2  = (const float*)d_in[8];
  const float* att2 = (const float*)d_in[9];
  const float* b2   = (const float*)d_in[10];
  const float* Wp   = (const float*)d_in[11];
  const float* bp   = (const float*)d_in[12];
  float* out = (float*)d_out;

  const int N = in_sizes[0] / 128;
  const int E = in_sizes[1] / 2;
  const int L = in_sizes[2] / 2;
  const int T = E + N;

  // workspace layout
  float* A = (float*)d_ws;            // [N*96] xl1, later xr2
  float* B = A + (size_t)N * 96;      // [N*96] xr1, later xl2
  float* C = B + (size_t)N * 96;      // [N*96] h1, later h2
  int* deg    = (int*)(C + (size_t)N * 96);  // [N]
  int* cnt    = deg + N;                     // [N]
  int* rowptr = cnt + N;                     // [N+1]
  int* ebuf   = rowptr + N + 1;              // [T] src per CSR slot

  const int BS = 256;
  const int GB = cdiv(N, 64);  // GEMM blocks (BM=64)

  // ---------------- CSR build (once, shared by both layers) ----------------
  hipMemsetAsync(deg, 0, (size_t)N * 4, stream);
  hipMemsetAsync(cnt, 0, (size_t)N * 4, stream);
  hist_kernel<<<cdiv(T, BS), BS, 0, stream>>>(ei, deg, E, N);
  scan_kernel<<<1, 1024, 0, stream>>>(deg, rowptr, N);
  fill_kernel<<<cdiv(T, BS), BS, 0, stream>>>(ei, cnt, rowptr, ebuf, E, N);

  // ---------------- layer 1 (128 -> 96) ----------------
  gemm_kernel<128, 96, 64, 64, 384><<<GB, 384, 0, stream>>>(x, Wl1, A, N);
  gemm_kernel<128, 96, 64, 64, 384><<<GB, 384, 0, stream>>>(x, Wr1, B, N);
  gat_fused_kernel<96><<<cdiv(N, BS / 64), BS, 0, stream>>>(A, B, rowptr, ebuf, att1, b1, C, N);

  // ---------------- layer 2 (96 -> 64) ----------------
  gemm_kernel<96, 64, 96, 64, 256><<<GB, 256, 0, stream>>>(C, Wl2, B, N);
  gemm_kernel<96, 64, 96, 64, 256><<<GB, 256, 0, stream>>>(C, Wr2, A, N);
  gat_fused_kernel<64><<<cdiv(N, BS / 64), BS, 0, stream>>>(B, A, rowptr, ebuf, att2, b2, C, N);

  // ---------------- link predictor ----------------
  predict_kernel<<<cdiv(L, BS), BS, 0, stream>>>(C, eli, Wp, bp, out, L);
}

// Round 6
// 381.381 us; speedup vs baseline: 7.3966x; 1.2535x over previous
//
#include <hip/hip_runtime.h>

#define NEG_SLOPE 0.2f

// ---------- register-tiled fp32 GEMM: Y[n,H] = X[n,K] @ W[K,H] ----------
template<int K, int H, int BK, int BM, int NT>
__global__ __launch_bounds__(NT) void gemm_kernel(const float* __restrict__ X,
                                                  const float* __restrict__ W,
                                                  float* __restrict__ Y, int n) {
  constexpr int TM = 4, TN = 4;
  constexpr int CG = H / TN;   // col groups
  constexpr int RG = BM / TM;  // row groups
  static_assert(CG * RG == NT, "thread grid mismatch");
  constexpr int XS = BM + 4;   // padded LDS stride
  __shared__ float Xs[BK][XS];
  __shared__ float Ws[BK][H];
  const int tid = threadIdx.x;
  const int row0 = blockIdx.x * BM;
  const int cg = tid % CG, rg = tid / CG;
  float acc[TM][TN] = {};

  for (int kc = 0; kc < K; kc += BK) {
    for (int i = tid; i < BK * H / 4; i += NT)
      ((float4*)&Ws[0][0])[i] = ((const float4*)(W + (size_t)kc * H))[i];
    for (int i = tid; i < BM * (BK / 4); i += NT) {
      int r = i / (BK / 4), kq = i % (BK / 4);
      int gr = row0 + r; if (gr >= n) gr = n - 1;
      float4 v = ((const float4*)(X + (size_t)gr * K + kc))[kq];
      Xs[kq * 4 + 0][r] = v.x;
      Xs[kq * 4 + 1][r] = v.y;
      Xs[kq * 4 + 2][r] = v.z;
      Xs[kq * 4 + 3][r] = v.w;
    }
    __syncthreads();
#pragma unroll 8
    for (int k = 0; k < BK; ++k) {
      float4 xv = *(const float4*)&Xs[k][rg * TM];
      float4 wv = *(const float4*)&Ws[k][cg * TN];
      acc[0][0] = fmaf(xv.x, wv.x, acc[0][0]);
      acc[0][1] = fmaf(xv.x, wv.y, acc[0][1]);
      acc[0][2] = fmaf(xv.x, wv.z, acc[0][2]);
      acc[0][3] = fmaf(xv.x, wv.w, acc[0][3]);
      acc[1][0] = fmaf(xv.y, wv.x, acc[1][0]);
      acc[1][1] = fmaf(xv.y, wv.y, acc[1][1]);
      acc[1][2] = fmaf(xv.y, wv.z, acc[1][2]);
      acc[1][3] = fmaf(xv.y, wv.w, acc[1][3]);
      acc[2][0] = fmaf(xv.z, wv.x, acc[2][0]);
      acc[2][1] = fmaf(xv.z, wv.y, acc[2][1]);
      acc[2][2] = fmaf(xv.z, wv.z, acc[2][2]);
      acc[2][3] = fmaf(xv.z, wv.w, acc[2][3]);
      acc[3][0] = fmaf(xv.w, wv.x, acc[3][0]);
      acc[3][1] = fmaf(xv.w, wv.y, acc[3][1]);
      acc[3][2] = fmaf(xv.w, wv.z, acc[3][2]);
      acc[3][3] = fmaf(xv.w, wv.w, acc[3][3]);
    }
    __syncthreads();
  }
  const int c0 = cg * TN;
#pragma unroll
  for (int i = 0; i < TM; ++i) {
    int gr = row0 + rg * TM + i;
    if (gr < n) {
      float4 o = make_float4(acc[i][0], acc[i][1], acc[i][2], acc[i][3]);
      *(float4*)(Y + (size_t)gr * H + c0) = o;
    }
  }
}

// ---------- CSR build: histogram of dst ----------
__global__ void hist_kernel(const int* __restrict__ ei, int* __restrict__ deg, int nE, int nN) {
  int t = blockIdx.x * blockDim.x + threadIdx.x;
  if (t >= nE + nN) return;
  int d = (t < nE) ? ei[nE + t] : (t - nE);
  atomicAdd(&deg[d], 1);
}

// ---------- CSR build: single-block streaming exclusive scan ----------
__global__ void scan_kernel(const int* __restrict__ deg, int* __restrict__ rowptr, int n) {
  __shared__ int wsum[16];
  __shared__ int carry_s;
  int lane = threadIdx.x & 63;
  int wid = threadIdx.x >> 6;
  if (threadIdx.x == 0) carry_s = 0;
  __syncthreads();
  for (int base = 0; base < n; base += 1024) {
    int i = base + threadIdx.x;
    int v = (i < n) ? deg[i] : 0;
    int sc = v;
#pragma unroll
    for (int off = 1; off < 64; off <<= 1) {
      int t = __shfl_up(sc, off);
      if (lane >= off) sc += t;
    }
    if (lane == 63) wsum[wid] = sc;
    __syncthreads();
    if (wid == 0 && lane < 16) {
      int w = wsum[lane];
#pragma unroll
      for (int off = 1; off < 16; off <<= 1) {
        int t = __shfl_up(w, off, 16);
        if (lane >= off) w += t;
      }
      wsum[lane] = w;
    }
    __syncthreads();
    int waveoff = (wid == 0) ? 0 : wsum[wid - 1];
    int total = wsum[15];
    int inc = carry_s + waveoff + sc;
    if (i < n) rowptr[i + 1] = inc;
    __syncthreads();
    if (threadIdx.x == 0) carry_s += total;
    __syncthreads();
  }
  if (threadIdx.x == 0) rowptr[0] = 0;
}

// ---------- CSR build: fill src ids into dst buckets ----------
__global__ void fill_kernel(const int* __restrict__ ei, int* __restrict__ cnt,
                            const int* __restrict__ rowptr, int* __restrict__ ebuf,
                            int nE, int nN) {
  int t = blockIdx.x * blockDim.x + threadIdx.x;
  if (t >= nE + nN) return;
  int s, d;
  if (t < nE) { s = ei[t]; d = ei[nE + t]; } else { s = t - nE; d = s; }
  int pos = rowptr[d] + atomicAdd(&cnt[d], 1);
  ebuf[pos] = s;
}

// ---------- fused GATv2 layer: one wave per dst node, online softmax, 4-edge ILP ----------
template<int H>
__global__ void gat_fused_kernel(const float* __restrict__ XL, const float* __restrict__ XR,
                                 const int* __restrict__ rowptr, const int* __restrict__ ebuf,
                                 const float* __restrict__ att, const float* __restrict__ bias,
                                 float* __restrict__ out, int nN) {
  int lane = threadIdx.x & 63;
  int wid = threadIdx.x >> 6;
  int d = blockIdx.x * (blockDim.x >> 6) + wid;
  if (d >= nN) return;
  constexpr bool TWO = (H > 64);
  const int c0 = lane;
  const int c1 = 64 + lane;
  const bool has1 = TWO && (lane < H - 64);
  float xr0 = XR[(size_t)d * H + c0];
  float xr1 = has1 ? XR[(size_t)d * H + c1] : 0.f;
  float a0 = att[c0];
  float a1 = has1 ? att[c1] : 0.f;
  float m = -1e30f, den = 0.f, o0 = 0.f, o1 = 0.f;
  int beg = rowptr[d], end = rowptr[d + 1];
  int cnt = end - beg;
  int head = beg + (cnt & 3);

  // remainder edges, one at a time
  for (int i = beg; i < head; ++i) {
    int s = ebuf[i];
    const float* xlr = XL + (size_t)s * H;
    float x0 = xlr[c0];
    float x1 = has1 ? xlr[c1] : 0.f;
    float f0 = x0 + xr0; f0 = f0 > 0.f ? f0 : NEG_SLOPE * f0;
    float part = f0 * a0;
    if (has1) { float f1 = x1 + xr1; f1 = f1 > 0.f ? f1 : NEG_SLOPE * f1; part = fmaf(f1, a1, part); }
#pragma unroll
    for (int off = 32; off; off >>= 1) part += __shfl_xor(part, off);
    if (part > m) {
      float scl = __expf(m - part);
      den *= scl; o0 *= scl; o1 *= scl; m = part;
    }
    float p = __expf(part - m);
    den += p;
    o0 = fmaf(p, x0, o0);
    if (has1) o1 = fmaf(p, x1, o1);
  }

  // main loop: 4 edges per iteration (independent gathers + reduces for MLP)
  for (int i = head; i < end; i += 4) {
    int s0 = ebuf[i + 0], s1 = ebuf[i + 1], s2 = ebuf[i + 2], s3 = ebuf[i + 3];
    const float* r0 = XL + (size_t)s0 * H;
    const float* r1 = XL + (size_t)s1 * H;
    const float* r2 = XL + (size_t)s2 * H;
    const float* r3 = XL + (size_t)s3 * H;
    float x00 = r0[c0], x01 = r1[c0], x02 = r2[c0], x03 = r3[c0];
    float x10 = 0.f, x11 = 0.f, x12 = 0.f, x13 = 0.f;
    if (has1) { x10 = r0[c1]; x11 = r1[c1]; x12 = r2[c1]; x13 = r3[c1]; }
    float f;
    f = x00 + xr0; f = f > 0.f ? f : NEG_SLOPE * f; float p0 = f * a0;
    f = x01 + xr0; f = f > 0.f ? f : NEG_SLOPE * f; float p1 = f * a0;
    f = x02 + xr0; f = f > 0.f ? f : NEG_SLOPE * f; float p2 = f * a0;
    f = x03 + xr0; f = f > 0.f ? f : NEG_SLOPE * f; float p3 = f * a0;
    if (has1) {
      f = x10 + xr1; f = f > 0.f ? f : NEG_SLOPE * f; p0 = fmaf(f, a1, p0);
      f = x11 + xr1; f = f > 0.f ? f : NEG_SLOPE * f; p1 = fmaf(f, a1, p1);
      f = x12 + xr1; f = f > 0.f ? f : NEG_SLOPE * f; p2 = fmaf(f, a1, p2);
      f = x13 + xr1; f = f > 0.f ? f : NEG_SLOPE * f; p3 = fmaf(f, a1, p3);
    }
#pragma unroll
    for (int off = 32; off; off >>= 1) {
      p0 += __shfl_xor(p0, off);
      p1 += __shfl_xor(p1, off);
      p2 += __shfl_xor(p2, off);
      p3 += __shfl_xor(p3, off);
    }
    float tmax = fmaxf(fmaxf(p0, p1), fmaxf(p2, p3));
    if (tmax > m) {
      float scl = __expf(m - tmax);
      den *= scl; o0 *= scl; o1 *= scl; m = tmax;
    }
    float e0 = __expf(p0 - m), e1 = __expf(p1 - m), e2 = __expf(p2 - m), e3 = __expf(p3 - m);
    den += (e0 + e1) + (e2 + e3);
    o0 = fmaf(e0, x00, o0); o0 = fmaf(e1, x01, o0);
    o0 = fmaf(e2, x02, o0); o0 = fmaf(e3, x03, o0);
    if (has1) {
      o1 = fmaf(e0, x10, o1); o1 = fmaf(e1, x11, o1);
      o1 = fmaf(e2, x12, o1); o1 = fmaf(e3, x13, o1);
    }
  }

  float inv = 1.f / (den + 1e-16f);
  float y0 = fmaf(o0, inv, bias[c0]); y0 = y0 > 0.f ? y0 : 0.f;
  out[(size_t)d * H + c0] = y0;
  if (has1) {
    float y1 = fmaf(o1, inv, bias[c1]); y1 = y1 > 0.f ? y1 : 0.f;
    out[(size_t)d * H + c1] = y1;
  }
}

// ---------- out[l] = sum_k hs[k]*hd[k]*(Wp[k,0]+Wp[k,1]) + bp0+bp1 ----------
__global__ void predict_kernel(const float* __restrict__ h, const int* __restrict__ eli,
                               const float* __restrict__ Wp, const float* __restrict__ bp,
                               float* __restrict__ out, int L) {
  int l = blockIdx.x * blockDim.x + threadIdx.x;
  if (l >= L) return;
  int s = eli[l], d = eli[L + l];
  const float4* a = (const float4*)(h + (size_t)s * 64);
  const float4* b = (const float4*)(h + (size_t)d * 64);
  const float4* wp = (const float4*)Wp;
  float acc = bp[0] + bp[1];
#pragma unroll
  for (int i = 0; i < 16; ++i) {
    float4 u = a[i], v = b[i];
    float4 w0 = wp[2 * i];
    float4 w1 = wp[2 * i + 1];
    acc = fmaf(u.x * v.x, w0.x + w0.y, acc);
    acc = fmaf(u.y * v.y, w0.z + w0.w, acc);
    acc = fmaf(u.z * v.z, w1.x + w1.y, acc);
    acc = fmaf(u.w * v.w, w1.z + w1.w, acc);
  }
  out[l] = acc;
}

static inline int cdiv(long long a, int b) { return (int)((a + b - 1) / b); }

extern "C" void kernel_launch(void* const* d_in, const int* in_sizes, int n_in,
                              void* d_out, int out_size, void* d_ws, size_t ws_size,
                              hipStream_t stream) {
  const float* x    = (const float*)d_in[0];
  const int*   ei   = (const int*)d_in[1];
  const int*   eli  = (const int*)d_in[2];
  const float* Wl1  = (const float*)d_in[3];
  const float* Wr1  = (const float*)d_in[4];
  const float* att1 = (const float*)d_in[5];
  const float* b1   = (const float*)d_in[6];
  const float* Wl2  = (const float*)d_in[7];
  const float* Wr2  = (const float*)d_in[8];
  const float* att2 = (const float*)d_in[9];
  const float* b2   = (const float*)d_in[10];
  const float* Wp   = (const float*)d_in[11];
  const float* bp   = (const float*)d_in[12];
  float* out = (float*)d_out;

  const int N = in_sizes[0] / 128;
  const int E = in_sizes[1] / 2;
  const int L = in_sizes[2] / 2;
  const int T = E + N;

  // workspace layout
  float* A = (float*)d_ws;            // [N*96] xl1, later xr2
  float* B = A + (size_t)N * 96;      // [N*96] xr1, later xl2
  float* C = B + (size_t)N * 96;      // [N*96] h1, later h2
  int* deg    = (int*)(C + (size_t)N * 96);  // [N]
  int* cnt    = deg + N;                     // [N]
  int* rowptr = cnt + N;                     // [N+1]
  int* ebuf   = rowptr + N + 1;              // [T] src per CSR slot

  const int BS = 256;
  const int GB = cdiv(N, 64);  // GEMM blocks (BM=64)

  // ---------------- CSR build (once, shared by both layers) ----------------
  hipMemsetAsync(deg, 0, (size_t)N * 4, stream);
  hipMemsetAsync(cnt, 0, (size_t)N * 4, stream);
  hist_kernel<<<cdiv(T, BS), BS, 0, stream>>>(ei, deg, E, N);
  scan_kernel<<<1, 1024, 0, stream>>>(deg, rowptr, N);
  fill_kernel<<<cdiv(T, BS), BS, 0, stream>>>(ei, cnt, rowptr, ebuf, E, N);

  // ---------------- layer 1 (128 -> 96) ----------------
  gemm_kernel<128, 96, 64, 64, 384><<<GB, 384, 0, stream>>>(x, Wl1, A, N);
  gemm_kernel<128, 96, 64, 64, 384><<<GB, 384, 0, stream>>>(x, Wr1, B, N);
  gat_fused_kernel<96><<<cdiv(N, BS / 64), BS, 0, stream>>>(A, B, rowptr, ebuf, att1, b1, C, N);

  // ---------------- layer 2 (96 -> 64) ----------------
  gemm_kernel<96, 64, 96, 64, 256><<<GB, 256, 0, stream>>>(C, Wl2, B, N);
  gemm_kernel<96, 64, 96, 64, 256><<<GB, 256, 0, stream>>>(C, Wr2, A, N);
  gat_fused_kernel<64><<<cdiv(N, BS / 64), BS, 0, stream>>>(B, A, rowptr, ebuf, att2, b2, C, N);

  // ---------------- link predictor ----------------
  predict_kernel<<<cdiv(L, BS), BS, 0, stream>>>(C, eli, Wp, bp, out, L);
}

// Round 7
// 316.387 us; speedup vs baseline: 8.9160x; 1.2054x over previous
//
#include <hip/hip_runtime.h>

#define NEG_SLOPE 0.2f

// ---------- dual-output register-tiled fp32 GEMM: Y1 = X@W1, Y2 = X@W2 ----------
// Shares the X LDS tile between both weight matrices: half the X traffic of
// two separate GEMMs and 32 FMAs per 3 ds_read_b128 in the inner loop.
template<int K, int H, int BK, int BM, int NT>
__global__ __launch_bounds__(NT) void gemm2_kernel(const float* __restrict__ X,
                                                   const float* __restrict__ W1,
                                                   const float* __restrict__ W2,
                                                   float* __restrict__ Y1,
                                                   float* __restrict__ Y2, int n) {
  constexpr int TM = 4, TN = 4;
  constexpr int CG = H / TN;
  constexpr int RG = BM / TM;
  static_assert(CG * RG == NT, "thread grid mismatch");
  constexpr int XS = BM + 4;  // padded LDS stride
  __shared__ float Xs[BK][XS];
  __shared__ float Ws1[BK][H];
  __shared__ float Ws2[BK][H];
  const int tid = threadIdx.x;
  const int row0 = blockIdx.x * BM;
  const int cg = tid % CG, rg = tid / CG;
  float acc1[TM][TN] = {};
  float acc2[TM][TN] = {};

  for (int kc = 0; kc < K; kc += BK) {
    for (int i = tid; i < BK * H / 4; i += NT) {
      ((float4*)&Ws1[0][0])[i] = ((const float4*)(W1 + (size_t)kc * H))[i];
      ((float4*)&Ws2[0][0])[i] = ((const float4*)(W2 + (size_t)kc * H))[i];
    }
    for (int i = tid; i < BM * (BK / 4); i += NT) {
      int r = i / (BK / 4), kq = i % (BK / 4);
      int gr = row0 + r; if (gr >= n) gr = n - 1;
      float4 v = ((const float4*)(X + (size_t)gr * K + kc))[kq];
      Xs[kq * 4 + 0][r] = v.x;
      Xs[kq * 4 + 1][r] = v.y;
      Xs[kq * 4 + 2][r] = v.z;
      Xs[kq * 4 + 3][r] = v.w;
    }
    __syncthreads();
#pragma unroll 8
    for (int k = 0; k < BK; ++k) {
      float4 xv = *(const float4*)&Xs[k][rg * TM];
      float4 wa = *(const float4*)&Ws1[k][cg * TN];
      float4 wb = *(const float4*)&Ws2[k][cg * TN];
#pragma unroll
      for (int i = 0; i < TM; ++i) {
        float xi = (i == 0) ? xv.x : (i == 1) ? xv.y : (i == 2) ? xv.z : xv.w;
        acc1[i][0] = fmaf(xi, wa.x, acc1[i][0]);
        acc1[i][1] = fmaf(xi, wa.y, acc1[i][1]);
        acc1[i][2] = fmaf(xi, wa.z, acc1[i][2]);
        acc1[i][3] = fmaf(xi, wa.w, acc1[i][3]);
        acc2[i][0] = fmaf(xi, wb.x, acc2[i][0]);
        acc2[i][1] = fmaf(xi, wb.y, acc2[i][1]);
        acc2[i][2] = fmaf(xi, wb.z, acc2[i][2]);
        acc2[i][3] = fmaf(xi, wb.w, acc2[i][3]);
      }
    }
    __syncthreads();
  }
  const int c0 = cg * TN;
#pragma unroll
  for (int i = 0; i < TM; ++i) {
    int gr = row0 + rg * TM + i;
    if (gr < n) {
      *(float4*)(Y1 + (size_t)gr * H + c0) = make_float4(acc1[i][0], acc1[i][1], acc1[i][2], acc1[i][3]);
      *(float4*)(Y2 + (size_t)gr * H + c0) = make_float4(acc2[i][0], acc2[i][1], acc2[i][2], acc2[i][3]);
    }
  }
}

// ---------- CSR build: histogram of dst ----------
__global__ void hist_kernel(const int* __restrict__ ei, int* __restrict__ deg, int nE, int nN) {
  int t = blockIdx.x * blockDim.x + threadIdx.x;
  if (t >= nE + nN) return;
  int d = (t < nE) ? ei[nE + t] : (t - nE);
  atomicAdd(&deg[d], 1);
}

// ---------- parallel scan, step 1: per-256-chunk sums ----------
__global__ void chunk_sum_kernel(const int* __restrict__ deg, int* __restrict__ psum, int n) {
  int c = blockIdx.x;
  int i = c * 256 + threadIdx.x;
  int lane = threadIdx.x & 63, wid = threadIdx.x >> 6;
  int v = (i < n) ? deg[i] : 0;
#pragma unroll
  for (int off = 32; off; off >>= 1) v += __shfl_xor(v, off);
  __shared__ int ws[4];
  if (lane == 0) ws[wid] = v;
  __syncthreads();
  if (threadIdx.x == 0) psum[c] = ws[0] + ws[1] + ws[2] + ws[3];
}

// ---------- block-wide inclusive scan helper (256 threads) ----------
__device__ __forceinline__ int block_incl_scan_256(int v) {
  int lane = threadIdx.x & 63, wid = threadIdx.x >> 6;
#pragma unroll
  for (int off = 1; off < 64; off <<= 1) {
    int t = __shfl_up(v, off);
    if (lane >= off) v += t;
  }
  __shared__ int wsum[4];
  if (lane == 63) wsum[wid] = v;
  __syncthreads();
  int add = 0;
  for (int w = 0; w < wid; ++w) add += wsum[w];
  return v + add;
}

// ---------- parallel scan, step 2: inclusive scan of chunk sums (nc <= 256) ----------
__global__ void scan_chunks_kernel(int* __restrict__ psum, int nc) {
  int i = threadIdx.x;
  int v = (i < nc) ? psum[i] : 0;
  int incl = block_incl_scan_256(v);
  if (i < nc) psum[i] = incl;
}

// ---------- parallel scan, step 3: intra-chunk scan + chunk offset -> rowptr ----------
__global__ void scan_final_kernel(const int* __restrict__ deg, const int* __restrict__ psum,
                                  int* __restrict__ rowptr, int n) {
  int c = blockIdx.x;
  int i = c * 256 + threadIdx.x;
  int v = (i < n) ? deg[i] : 0;
  int incl = block_incl_scan_256(v);
  int off = (c > 0) ? psum[c - 1] : 0;
  if (i < n) rowptr[i + 1] = off + incl;
  if (i == 0) rowptr[0] = 0;
}

// ---------- CSR build: fill src ids into dst buckets ----------
__global__ void fill_kernel(const int* __restrict__ ei, int* __restrict__ cnt,
                            const int* __restrict__ rowptr, int* __restrict__ ebuf,
                            int nE, int nN) {
  int t = blockIdx.x * blockDim.x + threadIdx.x;
  if (t >= nE + nN) return;
  int s, d;
  if (t < nE) { s = ei[t]; d = ei[nE + t]; } else { s = t - nE; d = s; }
  int pos = rowptr[d] + atomicAdd(&cnt[d], 1);
  ebuf[pos] = s;
}

// ---------- fused GATv2 layer: one wave per dst node, online softmax, 4-edge ILP ----------
template<int H>
__global__ void gat_fused_kernel(const float* __restrict__ XL, const float* __restrict__ XR,
                                 const int* __restrict__ rowptr, const int* __restrict__ ebuf,
                                 const float* __restrict__ att, const float* __restrict__ bias,
                                 float* __restrict__ out, int nN) {
  int lane = threadIdx.x & 63;
  int wid = threadIdx.x >> 6;
  int d = blockIdx.x * (blockDim.x >> 6) + wid;
  if (d >= nN) return;
  constexpr bool TWO = (H > 64);
  const int c0 = lane;
  const int c1 = 64 + lane;
  const bool has1 = TWO && (lane < H - 64);
  float xr0 = XR[(size_t)d * H + c0];
  float xr1 = has1 ? XR[(size_t)d * H + c1] : 0.f;
  float a0 = att[c0];
  float a1 = has1 ? att[c1] : 0.f;
  float m = -1e30f, den = 0.f, o0 = 0.f, o1 = 0.f;
  int beg = rowptr[d], end = rowptr[d + 1];
  int cnt = end - beg;
  int head = beg + (cnt & 3);

  for (int i = beg; i < head; ++i) {
    int s = ebuf[i];
    const float* xlr = XL + (size_t)s * H;
    float x0 = xlr[c0];
    float x1 = has1 ? xlr[c1] : 0.f;
    float f0 = x0 + xr0; f0 = f0 > 0.f ? f0 : NEG_SLOPE * f0;
    float part = f0 * a0;
    if (has1) { float f1 = x1 + xr1; f1 = f1 > 0.f ? f1 : NEG_SLOPE * f1; part = fmaf(f1, a1, part); }
#pragma unroll
    for (int off = 32; off; off >>= 1) part += __shfl_xor(part, off);
    if (part > m) {
      float scl = __expf(m - part);
      den *= scl; o0 *= scl; o1 *= scl; m = part;
    }
    float p = __expf(part - m);
    den += p;
    o0 = fmaf(p, x0, o0);
    if (has1) o1 = fmaf(p, x1, o1);
  }

  for (int i = head; i < end; i += 4) {
    int s0 = ebuf[i + 0], s1 = ebuf[i + 1], s2 = ebuf[i + 2], s3 = ebuf[i + 3];
    const float* r0 = XL + (size_t)s0 * H;
    const float* r1 = XL + (size_t)s1 * H;
    const float* r2 = XL + (size_t)s2 * H;
    const float* r3 = XL + (size_t)s3 * H;
    float x00 = r0[c0], x01 = r1[c0], x02 = r2[c0], x03 = r3[c0];
    float x10 = 0.f, x11 = 0.f, x12 = 0.f, x13 = 0.f;
    if (has1) { x10 = r0[c1]; x11 = r1[c1]; x12 = r2[c1]; x13 = r3[c1]; }
    float f;
    f = x00 + xr0; f = f > 0.f ? f : NEG_SLOPE * f; float p0 = f * a0;
    f = x01 + xr0; f = f > 0.f ? f : NEG_SLOPE * f; float p1 = f * a0;
    f = x02 + xr0; f = f > 0.f ? f : NEG_SLOPE * f; float p2 = f * a0;
    f = x03 + xr0; f = f > 0.f ? f : NEG_SLOPE * f; float p3 = f * a0;
    if (has1) {
      f = x10 + xr1; f = f > 0.f ? f : NEG_SLOPE * f; p0 = fmaf(f, a1, p0);
      f = x11 + xr1; f = f > 0.f ? f : NEG_SLOPE * f; p1 = fmaf(f, a1, p1);
      f = x12 + xr1; f = f > 0.f ? f : NEG_SLOPE * f; p2 = fmaf(f, a1, p2);
      f = x13 + xr1; f = f > 0.f ? f : NEG_SLOPE * f; p3 = fmaf(f, a1, p3);
    }
#pragma unroll
    for (int off = 32; off; off >>= 1) {
      p0 += __shfl_xor(p0, off);
      p1 += __shfl_xor(p1, off);
      p2 += __shfl_xor(p2, off);
      p3 += __shfl_xor(p3, off);
    }
    float tmax = fmaxf(fmaxf(p0, p1), fmaxf(p2, p3));
    if (tmax > m) {
      float scl = __expf(m - tmax);
      den *= scl; o0 *= scl; o1 *= scl; m = tmax;
    }
    float e0 = __expf(p0 - m), e1 = __expf(p1 - m), e2 = __expf(p2 - m), e3 = __expf(p3 - m);
    den += (e0 + e1) + (e2 + e3);
    o0 = fmaf(e0, x00, o0); o0 = fmaf(e1, x01, o0);
    o0 = fmaf(e2, x02, o0); o0 = fmaf(e3, x03, o0);
    if (has1) {
      o1 = fmaf(e0, x10, o1); o1 = fmaf(e1, x11, o1);
      o1 = fmaf(e2, x12, o1); o1 = fmaf(e3, x13, o1);
    }
  }

  float inv = 1.f / (den + 1e-16f);
  float y0 = fmaf(o0, inv, bias[c0]); y0 = y0 > 0.f ? y0 : 0.f;
  out[(size_t)d * H + c0] = y0;
  if (has1) {
    float y1 = fmaf(o1, inv, bias[c1]); y1 = y1 > 0.f ? y1 : 0.f;
    out[(size_t)d * H + c1] = y1;
  }
}

// ---------- out[l] = sum_k hs[k]*hd[k]*(Wp[k,0]+Wp[k,1]) + bp0+bp1 ----------
__global__ void predict_kernel(const float* __restrict__ h, const int* __restrict__ eli,
                               const float* __restrict__ Wp, const float* __restrict__ bp,
                               float* __restrict__ out, int L) {
  int l = blockIdx.x * blockDim.x + threadIdx.x;
  if (l >= L) return;
  int s = eli[l], d = eli[L + l];
  const float4* a = (const float4*)(h + (size_t)s * 64);
  const float4* b = (const float4*)(h + (size_t)d * 64);
  const float4* wp = (const float4*)Wp;
  float acc = bp[0] + bp[1];
#pragma unroll
  for (int i = 0; i < 16; ++i) {
    float4 u = a[i], v = b[i];
    float4 w0 = wp[2 * i];
    float4 w1 = wp[2 * i + 1];
    acc = fmaf(u.x * v.x, w0.x + w0.y, acc);
    acc = fmaf(u.y * v.y, w0.z + w0.w, acc);
    acc = fmaf(u.z * v.z, w1.x + w1.y, acc);
    acc = fmaf(u.w * v.w, w1.z + w1.w, acc);
  }
  out[l] = acc;
}

static inline int cdiv(long long a, int b) { return (int)((a + b - 1) / b); }

extern "C" void kernel_launch(void* const* d_in, const int* in_sizes, int n_in,
                              void* d_out, int out_size, void* d_ws, size_t ws_size,
                              hipStream_t stream) {
  const float* x    = (const float*)d_in[0];
  const int*   ei   = (const int*)d_in[1];
  const int*   eli  = (const int*)d_in[2];
  const float* Wl1  = (const float*)d_in[3];
  const float* Wr1  = (const float*)d_in[4];
  const float* att1 = (const float*)d_in[5];
  const float* b1   = (const float*)d_in[6];
  const float* Wl2  = (const float*)d_in[7];
  const float* Wr2  = (const float*)d_in[8];
  const float* att2 = (const float*)d_in[9];
  const float* b2   = (const float*)d_in[10];
  const float* Wp   = (const float*)d_in[11];
  const float* bp   = (const float*)d_in[12];
  float* out = (float*)d_out;

  const int N = in_sizes[0] / 128;
  const int E = in_sizes[1] / 2;
  const int L = in_sizes[2] / 2;
  const int T = E + N;
  const int NC = cdiv(N, 256);  // scan chunks (must be <= 256; N=50000 -> 196)

  // workspace layout
  float* A = (float*)d_ws;            // [N*96] xl1, later xr2
  float* B = A + (size_t)N * 96;      // [N*96] xr1, later xl2
  float* C = B + (size_t)N * 96;      // [N*96] h1, later h2
  int* deg    = (int*)(C + (size_t)N * 96);  // [N]
  int* cnt    = deg + N;                     // [N]
  int* rowptr = cnt + N;                     // [N+1]
  int* ebuf   = rowptr + N + 1;              // [T]
  int* psum   = ebuf + T;                    // [NC]

  const int BS = 256;
  const int GB = cdiv(N, 64);  // GEMM blocks (BM=64)

  // ---------------- CSR build (once, shared by both layers) ----------------
  hipMemsetAsync(deg, 0, (size_t)N * 4, stream);
  hipMemsetAsync(cnt, 0, (size_t)N * 4, stream);
  hist_kernel<<<cdiv(T, BS), BS, 0, stream>>>(ei, deg, E, N);
  chunk_sum_kernel<<<NC, 256, 0, stream>>>(deg, psum, N);
  scan_chunks_kernel<<<1, 256, 0, stream>>>(psum, NC);
  scan_final_kernel<<<NC, 256, 0, stream>>>(deg, psum, rowptr, N);
  fill_kernel<<<cdiv(T, BS), BS, 0, stream>>>(ei, cnt, rowptr, ebuf, E, N);

  // ---------------- layer 1 (128 -> 96) ----------------
  gemm2_kernel<128, 96, 32, 64, 384><<<GB, 384, 0, stream>>>(x, Wl1, Wr1, A, B, N);
  gat_fused_kernel<96><<<cdiv(N, BS / 64), BS, 0, stream>>>(A, B, rowptr, ebuf, att1, b1, C, N);

  // ---------------- layer 2 (96 -> 64) ----------------
  gemm2_kernel<96, 64, 48, 64, 256><<<GB, 256, 0, stream>>>(C, Wl2, Wr2, B, A, N);
  gat_fused_kernel<64><<<cdiv(N, BS / 64), BS, 0, stream>>>(B, A, rowptr, ebuf, att2, b2, C, N);

  // ---------------- link predictor ----------------
  predict_kernel<<<cdiv(L, BS), BS, 0, stream>>>(C, eli, Wp, bp, out, L);
}

// Round 9
// 282.694 us; speedup vs baseline: 9.9787x; 1.1192x over previous
//
#include <hip/hip_runtime.h>

#define NEG_SLOPE 0.2f

// ---------- dual-output register-tiled fp32 GEMM: Y1 = X@W1, Y2 = X@W2 ----------
template<int K, int H, int BK, int BM, int NT>
__global__ __launch_bounds__(NT) void gemm2_kernel(const float* __restrict__ X,
                                                   const float* __restrict__ W1,
                                                   const float* __restrict__ W2,
                                                   float* __restrict__ Y1,
                                                   float* __restrict__ Y2, int n) {
  constexpr int TM = 4, TN = 4;
  constexpr int CG = H / TN;
  constexpr int RG = BM / TM;
  static_assert(CG * RG == NT, "thread grid mismatch");
  constexpr int XS = BM + 4;
  __shared__ float Xs[BK][XS];
  __shared__ float Ws1[BK][H];
  __shared__ float Ws2[BK][H];
  const int tid = threadIdx.x;
  const int row0 = blockIdx.x * BM;
  const int cg = tid % CG, rg = tid / CG;
  float acc1[TM][TN] = {};
  float acc2[TM][TN] = {};

  for (int kc = 0; kc < K; kc += BK) {
    for (int i = tid; i < BK * H / 4; i += NT) {
      ((float4*)&Ws1[0][0])[i] = ((const float4*)(W1 + (size_t)kc * H))[i];
      ((float4*)&Ws2[0][0])[i] = ((const float4*)(W2 + (size_t)kc * H))[i];
    }
    for (int i = tid; i < BM * (BK / 4); i += NT) {
      int r = i / (BK / 4), kq = i % (BK / 4);
      int gr = row0 + r; if (gr >= n) gr = n - 1;
      float4 v = ((const float4*)(X + (size_t)gr * K + kc))[kq];
      Xs[kq * 4 + 0][r] = v.x;
      Xs[kq * 4 + 1][r] = v.y;
      Xs[kq * 4 + 2][r] = v.z;
      Xs[kq * 4 + 3][r] = v.w;
    }
    __syncthreads();
#pragma unroll 8
    for (int k = 0; k < BK; ++k) {
      float4 xv = *(const float4*)&Xs[k][rg * TM];
      float4 wa = *(const float4*)&Ws1[k][cg * TN];
      float4 wb = *(const float4*)&Ws2[k][cg * TN];
#pragma unroll
      for (int i = 0; i < TM; ++i) {
        float xi = (i == 0) ? xv.x : (i == 1) ? xv.y : (i == 2) ? xv.z : xv.w;
        acc1[i][0] = fmaf(xi, wa.x, acc1[i][0]);
        acc1[i][1] = fmaf(xi, wa.y, acc1[i][1]);
        acc1[i][2] = fmaf(xi, wa.z, acc1[i][2]);
        acc1[i][3] = fmaf(xi, wa.w, acc1[i][3]);
        acc2[i][0] = fmaf(xi, wb.x, acc2[i][0]);
        acc2[i][1] = fmaf(xi, wb.y, acc2[i][1]);
        acc2[i][2] = fmaf(xi, wb.z, acc2[i][2]);
        acc2[i][3] = fmaf(xi, wb.w, acc2[i][3]);
      }
    }
    __syncthreads();
  }
  const int c0 = cg * TN;
#pragma unroll
  for (int i = 0; i < TM; ++i) {
    int gr = row0 + rg * TM + i;
    if (gr < n) {
      *(float4*)(Y1 + (size_t)gr * H + c0) = make_float4(acc1[i][0], acc1[i][1], acc1[i][2], acc1[i][3]);
      *(float4*)(Y2 + (size_t)gr * H + c0) = make_float4(acc2[i][0], acc2[i][1], acc2[i][2], acc2[i][3]);
    }
  }
}

// ---------- CSR build: histogram of dst ----------
__global__ void hist_kernel(const int* __restrict__ ei, int* __restrict__ deg, int nE, int nN) {
  int t = blockIdx.x * blockDim.x + threadIdx.x;
  if (t >= nE + nN) return;
  int d = (t < nE) ? ei[nE + t] : (t - nE);
  atomicAdd(&deg[d], 1);
}

// ---------- parallel scan, step 1: per-256-chunk sums ----------
__global__ void chunk_sum_kernel(const int* __restrict__ deg, int* __restrict__ psum, int n) {
  int c = blockIdx.x;
  int i = c * 256 + threadIdx.x;
  int lane = threadIdx.x & 63, wid = threadIdx.x >> 6;
  int v = (i < n) ? deg[i] : 0;
#pragma unroll
  for (int off = 32; off; off >>= 1) v += __shfl_xor(v, off);
  __shared__ int ws[4];
  if (lane == 0) ws[wid] = v;
  __syncthreads();
  if (threadIdx.x == 0) psum[c] = ws[0] + ws[1] + ws[2] + ws[3];
}

// ---------- block-wide inclusive scan helper (256 threads) ----------
__device__ __forceinline__ int block_incl_scan_256(int v) {
  int lane = threadIdx.x & 63, wid = threadIdx.x >> 6;
#pragma unroll
  for (int off = 1; off < 64; off <<= 1) {
    int t = __shfl_up(v, off);
    if (lane >= off) v += t;
  }
  __shared__ int wsum[4];
  if (lane == 63) wsum[wid] = v;
  __syncthreads();
  int add = 0;
  for (int w = 0; w < wid; ++w) add += wsum[w];
  return v + add;
}

// ---------- parallel scan, step 2: inclusive scan of chunk sums (nc <= 256) ----------
__global__ void scan_chunks_kernel(int* __restrict__ psum, int nc) {
  int i = threadIdx.x;
  int v = (i < nc) ? psum[i] : 0;
  int incl = block_incl_scan_256(v);
  if (i < nc) psum[i] = incl;
}

// ---------- parallel scan, step 3: intra-chunk scan + chunk offset -> rowptr ----------
__global__ void scan_final_kernel(const int* __restrict__ deg, const int* __restrict__ psum,
                                  int* __restrict__ rowptr, int n) {
  int c = blockIdx.x;
  int i = c * 256 + threadIdx.x;
  int v = (i < n) ? deg[i] : 0;
  int incl = block_incl_scan_256(v);
  int off = (c > 0) ? psum[c - 1] : 0;
  if (i < n) rowptr[i + 1] = off + incl;
  if (i == 0) rowptr[0] = 0;
}

// ---------- CSR build: fill src ids into dst buckets ----------
__global__ void fill_kernel(const int* __restrict__ ei, int* __restrict__ cnt,
                            const int* __restrict__ rowptr, int* __restrict__ ebuf,
                            int nE, int nN) {
  int t = blockIdx.x * blockDim.x + threadIdx.x;
  if (t >= nE + nN) return;
  int s, d;
  if (t < nE) { s = ei[t]; d = ei[nE + t]; } else { s = t - nE; d = s; }
  int pos = rowptr[d] + atomicAdd(&cnt[d], 1);
  ebuf[pos] = s;
}

// ---------- fused GATv2 layer: wave per dst node, 4x16-lane edge groups ----------
// Each 16-lane group processes every 4th edge; lane owns 6 channels (f4+f2 for
// H=96, f4 for H=64). Logit reduce = 4 shfl steps (within group). Per-group
// online softmax; one 4-way flash-merge (xor 16, 32) at the end.
template<int H>
__global__ void gat_fused_kernel(const float* __restrict__ XL, const float* __restrict__ XR,
                                 const int* __restrict__ rowptr, const int* __restrict__ ebuf,
                                 const float* __restrict__ att, const float* __restrict__ bias,
                                 float* __restrict__ out, int nN) {
  constexpr bool HAS2 = (H > 64);
  int lane = threadIdx.x & 63;
  int wid = threadIdx.x >> 6;
  int d = blockIdx.x * (blockDim.x >> 6) + wid;
  if (d >= nN) return;
  int g = lane >> 4;   // edge group 0..3
  int ll = lane & 15;  // lane within group
  const int cA = ll * 4;
  const int cB = 64 + ll * 2;

  const float* xrrow = XR + (size_t)d * H;
  float4 xr4 = *(const float4*)(xrrow + cA);
  float4 a4 = *(const float4*)(att + cA);
  float4 s4 = make_float4(a4.x * NEG_SLOPE, a4.y * NEG_SLOPE, a4.z * NEG_SLOPE, a4.w * NEG_SLOPE);
  float2 xr2 = make_float2(0.f, 0.f), a2 = make_float2(0.f, 0.f), s2 = make_float2(0.f, 0.f);
  if constexpr (HAS2) {
    xr2 = *(const float2*)(xrrow + cB);
    a2 = *(const float2*)(att + cB);
    s2 = make_float2(a2.x * NEG_SLOPE, a2.y * NEG_SLOPE);
  }

  float m = -1e30f, den = 0.f;
  float4 o4 = make_float4(0.f, 0.f, 0.f, 0.f);
  float2 o2 = make_float2(0.f, 0.f);

  int beg = rowptr[d], end = rowptr[d + 1];
  int i = beg + g;
  int s = (i < end) ? ebuf[i] : 0;
  while (i < end) {
    int inext = i + 4;
    int snext = (inext < end) ? ebuf[inext] : 0;
    const float* R = XL + (size_t)s * H;
    float4 x4 = *(const float4*)(R + cA);
    float2 x2 = make_float2(0.f, 0.f);
    if constexpr (HAS2) x2 = *(const float2*)(R + cB);
    // p = sum_c att_c * leakyrelu(x_c + xr_c); lrelu = a*max(f,0) + 0.2a*min(f,0)
    float f, p;
    f = x4.x + xr4.x; p = fmaf(fmaxf(f, 0.f), a4.x, fminf(f, 0.f) * s4.x);
    f = x4.y + xr4.y; p = fmaf(fmaxf(f, 0.f), a4.y, fmaf(fminf(f, 0.f), s4.y, p));
    f = x4.z + xr4.z; p = fmaf(fmaxf(f, 0.f), a4.z, fmaf(fminf(f, 0.f), s4.z, p));
    f = x4.w + xr4.w; p = fmaf(fmaxf(f, 0.f), a4.w, fmaf(fminf(f, 0.f), s4.w, p));
    if constexpr (HAS2) {
      f = x2.x + xr2.x; p = fmaf(fmaxf(f, 0.f), a2.x, fmaf(fminf(f, 0.f), s2.x, p));
      f = x2.y + xr2.y; p = fmaf(fmaxf(f, 0.f), a2.y, fmaf(fminf(f, 0.f), s2.y, p));
    }
    // reduce within 16-lane group
    p += __shfl_xor(p, 1);
    p += __shfl_xor(p, 2);
    p += __shfl_xor(p, 4);
    p += __shfl_xor(p, 8);
    // online softmax update (uniform within group)
    if (p > m) {
      float scl = __expf(m - p);
      den *= scl;
      o4.x *= scl; o4.y *= scl; o4.z *= scl; o4.w *= scl;
      if constexpr (HAS2) { o2.x *= scl; o2.y *= scl; }
      m = p;
    }
    float w = __expf(p - m);
    den += w;
    o4.x = fmaf(w, x4.x, o4.x); o4.y = fmaf(w, x4.y, o4.y);
    o4.z = fmaf(w, x4.z, o4.z); o4.w = fmaf(w, x4.w, o4.w);
    if constexpr (HAS2) { o2.x = fmaf(w, x2.x, o2.x); o2.y = fmaf(w, x2.y, o2.y); }
    i = inext;
    s = snext;
  }

  // merge the 4 groups (flash-style), xor 16 then xor 32
#pragma unroll
  for (int msk = 16; msk <= 32; msk <<= 1) {
    float m2 = __shfl_xor(m, msk);
    float den2 = __shfl_xor(den, msk);
    float q0 = __shfl_xor(o4.x, msk), q1 = __shfl_xor(o4.y, msk);
    float q2 = __shfl_xor(o4.z, msk), q3 = __shfl_xor(o4.w, msk);
    float q4 = 0.f, q5 = 0.f;
    if constexpr (HAS2) { q4 = __shfl_xor(o2.x, msk); q5 = __shfl_xor(o2.y, msk); }
    float M = fmaxf(m, m2);
    float sa = __expf(m - M), sb = __expf(m2 - M);
    den = den * sa + den2 * sb;
    o4.x = o4.x * sa + q0 * sb; o4.y = o4.y * sa + q1 * sb;
    o4.z = o4.z * sa + q2 * sb; o4.w = o4.w * sa + q3 * sb;
    if constexpr (HAS2) { o2.x = o2.x * sa + q4 * sb; o2.y = o2.y * sa + q5 * sb; }
    m = M;
  }

  if (g == 0) {
    float inv = 1.f / (den + 1e-16f);
    float4 b4 = *(const float4*)(bias + cA);
    float4 y;
    y.x = fmaf(o4.x, inv, b4.x); y.x = y.x > 0.f ? y.x : 0.f;
    y.y = fmaf(o4.y, inv, b4.y); y.y = y.y > 0.f ? y.y : 0.f;
    y.z = fmaf(o4.z, inv, b4.z); y.z = y.z > 0.f ? y.z : 0.f;
    y.w = fmaf(o4.w, inv, b4.w); y.w = y.w > 0.f ? y.w : 0.f;
    *(float4*)(out + (size_t)d * H + cA) = y;
    if constexpr (HAS2) {
      float2 b2 = *(const float2*)(bias + cB);
      float2 z;
      z.x = fmaf(o2.x, inv, b2.x); z.x = z.x > 0.f ? z.x : 0.f;
      z.y = fmaf(o2.y, inv, b2.y); z.y = z.y > 0.f ? z.y : 0.f;
      *(float2*)(out + (size_t)d * H + cB) = z;
    }
  }
}

// ---------- out[l] = sum_k hs[k]*hd[k]*(Wp[k,0]+Wp[k,1]) + bp0+bp1 ----------
__global__ void predict_kernel(const float* __restrict__ h, const int* __restrict__ eli,
                               const float* __restrict__ Wp, const float* __restrict__ bp,
                               float* __restrict__ out, int L) {
  int l = blockIdx.x * blockDim.x + threadIdx.x;
  if (l >= L) return;
  int s = eli[l], d = eli[L + l];
  const float4* a = (const float4*)(h + (size_t)s * 64);
  const float4* b = (const float4*)(h + (size_t)d * 64);
  const float4* wp = (const float4*)Wp;
  float acc = bp[0] + bp[1];
#pragma unroll
  for (int i = 0; i < 16; ++i) {
    float4 u = a[i], v = b[i];
    float4 w0 = wp[2 * i];
    float4 w1 = wp[2 * i + 1];
    acc = fmaf(u.x * v.x, w0.x + w0.y, acc);
    acc = fmaf(u.y * v.y, w0.z + w0.w, acc);
    acc = fmaf(u.z * v.z, w1.x + w1.y, acc);
    acc = fmaf(u.w * v.w, w1.z + w1.w, acc);
  }
  out[l] = acc;
}

static inline int cdiv(long long a, int b) { return (int)((a + b - 1) / b); }

extern "C" void kernel_launch(void* const* d_in, const int* in_sizes, int n_in,
                              void* d_out, int out_size, void* d_ws, size_t ws_size,
                              hipStream_t stream) {
  const float* x    = (const float*)d_in[0];
  const int*   ei   = (const int*)d_in[1];
  const int*   eli  = (const int*)d_in[2];
  const float* Wl1  = (const float*)d_in[3];
  const float* Wr1  = (const float*)d_in[4];
  const float* att1 = (const float*)d_in[5];
  const float* b1   = (const float*)d_in[6];
  const float* Wl2  = (const float*)d_in[7];
  const float* Wr2  = (const float*)d_in[8];
  const float* att2 = (const float*)d_in[9];
  const float* b2   = (const float*)d_in[10];
  const float* Wp   = (const float*)d_in[11];
  const float* bp   = (const float*)d_in[12];
  float* out = (float*)d_out;

  const int N = in_sizes[0] / 128;
  const int E = in_sizes[1] / 2;
  const int L = in_sizes[2] / 2;
  const int T = E + N;
  const int NC = cdiv(N, 256);

  // workspace layout
  float* A = (float*)d_ws;            // [N*96] xl1, later xr2
  float* B = A + (size_t)N * 96;      // [N*96] xr1, later xl2
  float* C = B + (size_t)N * 96;      // [N*96] h1, later h2
  int* deg    = (int*)(C + (size_t)N * 96);  // [N]
  int* cnt    = deg + N;                     // [N]
  int* rowptr = cnt + N;                     // [N+1]
  int* ebuf   = rowptr + N + 1;              // [T]
  int* psum   = ebuf + T;                    // [NC]

  const int BS = 256;
  const int GB = cdiv(N, 64);

  // ---------------- CSR build (once, shared by both layers) ----------------
  hipMemsetAsync(deg, 0, (size_t)N * 4, stream);
  hipMemsetAsync(cnt, 0, (size_t)N * 4, stream);
  hist_kernel<<<cdiv(T, BS), BS, 0, stream>>>(ei, deg, E, N);
  chunk_sum_kernel<<<NC, 256, 0, stream>>>(deg, psum, N);
  scan_chunks_kernel<<<1, 256, 0, stream>>>(psum, NC);
  scan_final_kernel<<<NC, 256, 0, stream>>>(deg, psum, rowptr, N);
  fill_kernel<<<cdiv(T, BS), BS, 0, stream>>>(ei, cnt, rowptr, ebuf, E, N);

  // ---------------- layer 1 (128 -> 96) ----------------
  gemm2_kernel<128, 96, 32, 64, 384><<<GB, 384, 0, stream>>>(x, Wl1, Wr1, A, B, N);
  gat_fused_kernel<96><<<cdiv(N, BS / 64), BS, 0, stream>>>(A, B, rowptr, ebuf, att1, b1, C, N);

  // ---------------- layer 2 (96 -> 64) ----------------
  gemm2_kernel<96, 64, 48, 64, 256><<<GB, 256, 0, stream>>>(C, Wl2, Wr2, B, A, N);
  gat_fused_kernel<64><<<cdiv(N, BS / 64), BS, 0, stream>>>(B, A, rowptr, ebuf, att2, b2, C, N);

  // ---------------- link predictor ----------------
  predict_kernel<<<cdiv(L, BS), BS, 0, stream>>>(C, eli, Wp, bp, out, L);
}